// Round 1
// baseline (209.983 us; speedup 1.0000x reference)
//
#include <hip/hip_runtime.h>
#include <hip/hip_bf16.h>

// Problem constants
#define BB 4
#define CIN 256      // CK == CQ == CV
#define CO 64
#define NN 576       // H*W = 24*24, Nk == Nq

// out[b, n, o] = sum_c x[b, c, n] * W[o, c] + bias[o]
// grid: BB*NN blocks, 64 threads (one per o)
__global__ void proj_kernel(const float* __restrict__ x,
                            const float* __restrict__ W,
                            const float* __restrict__ bias,
                            float* __restrict__ out) {
    int bn = blockIdx.x;              // b*NN + n
    int b  = bn / NN;
    int n  = bn % NN;
    int o  = threadIdx.x;             // 0..63

    __shared__ float xcol[CIN];
    const float* xb = x + (size_t)b * CIN * NN + n;
    #pragma unroll
    for (int j = 0; j < CIN / 64; ++j) {
        int c = j * 64 + threadIdx.x;
        xcol[c] = xb[(size_t)c * NN];
    }
    __syncthreads();

    const float4* W4 = (const float4*)(W + (size_t)o * CIN);
    const float4* x4 = (const float4*)xcol;
    float acc = bias[o];
    #pragma unroll
    for (int i = 0; i < CIN / 4; ++i) {
        float4 w = W4[i];
        float4 xv = x4[i];
        acc += w.x * xv.x + w.y * xv.y + w.z * xv.z + w.w * xv.w;
    }
    out[(size_t)bn * CO + o] = acc;
}

__device__ __forceinline__ float fast_tanh(float x) {
    // tanh(x) = 1 - 2/(exp(2x)+1); __expf -> native v_exp_f32 path
    float e = __expf(2.0f * x);
    return 1.0f - 2.0f / (e + 1.0f);
}

// attn[b, k, q] = sigmoid( sum_o tanh(kp[b,k,o] + qp[b,q,o]) * wf[o] + bf )
// grid: (BB*NN, NN/64); block: 64 threads (one per q in tile)
__global__ void attn_kernel(const float* __restrict__ kp,
                            const float* __restrict__ qp,
                            const float* __restrict__ wf,
                            const float* __restrict__ bfp,
                            float* __restrict__ attn) {
    int bk = blockIdx.x;              // b*NN + k
    int b  = bk / NN;
    int q  = blockIdx.y * 64 + threadIdx.x;

    __shared__ float kcol[CO];
    __shared__ float wfs[CO];
    kcol[threadIdx.x] = kp[(size_t)bk * CO + threadIdx.x];
    wfs[threadIdx.x]  = wf[threadIdx.x];
    __syncthreads();

    // stage this thread's q-row (64 contiguous floats) into registers
    const float4* q4 = (const float4*)(qp + ((size_t)b * NN + q) * CO);
    float4 qv[CO / 4];
    #pragma unroll
    for (int i = 0; i < CO / 4; ++i) qv[i] = q4[i];
    const float* qs = (const float*)qv;

    float acc = bfp[0];
    #pragma unroll
    for (int o = 0; o < CO; ++o) {
        float t = fast_tanh(kcol[o] + qs[o]);
        acc += t * wfs[o];
    }
    float s = 1.0f / (1.0f + __expf(-acc));
    attn[((size_t)b * NN + bk % NN) * NN + q] = s;
}

// out[b, c, q] = sum_k attn[b, k, q] * value[b, c, k]
// grid: (NN/64, CV/4, BB); block: 64 threads (one per q), 4 c-rows per block
__global__ void av_kernel(const float* __restrict__ attn,
                          const float* __restrict__ value,
                          float* __restrict__ out) {
    int q  = blockIdx.x * 64 + threadIdx.x;
    int c0 = blockIdx.y * 4;
    int b  = blockIdx.z;

    __shared__ float vrow[4 * NN];
    const float* vbase = value + ((size_t)b * CIN + c0) * NN;
    for (int i = threadIdx.x; i < 4 * NN; i += 64) vrow[i] = vbase[i];
    __syncthreads();

    float acc0 = 0.f, acc1 = 0.f, acc2 = 0.f, acc3 = 0.f;
    const float* ab = attn + (size_t)b * NN * NN + q;
    #pragma unroll 4
    for (int k = 0; k < NN; ++k) {
        float a = ab[(size_t)k * NN];
        acc0 += a * vrow[0 * NN + k];
        acc1 += a * vrow[1 * NN + k];
        acc2 += a * vrow[2 * NN + k];
        acc3 += a * vrow[3 * NN + k];
    }
    size_t ob = ((size_t)b * CIN + c0) * NN + q;
    out[ob + 0 * NN] = acc0;
    out[ob + 1 * NN] = acc1;
    out[ob + 2 * NN] = acc2;
    out[ob + 3 * NN] = acc3;
}

extern "C" void kernel_launch(void* const* d_in, const int* in_sizes, int n_in,
                              void* d_out, int out_size, void* d_ws, size_t ws_size,
                              hipStream_t stream) {
    const float* key   = (const float*)d_in[0];
    const float* query = (const float*)d_in[1];
    const float* value = (const float*)d_in[2];
    const float* Wk    = (const float*)d_in[3];
    const float* bk    = (const float*)d_in[4];
    const float* Wq    = (const float*)d_in[5];
    const float* bq    = (const float*)d_in[6];
    const float* wf    = (const float*)d_in[7];
    const float* bf    = (const float*)d_in[8];
    float* out = (float*)d_out;

    float* ws   = (float*)d_ws;
    float* kp   = ws;                            // B*N*CO = 147456 floats
    float* qp   = kp + (size_t)BB * NN * CO;     // 147456 floats
    float* attn = qp + (size_t)BB * NN * CO;     // B*N*N = 1327104 floats

    proj_kernel<<<BB * NN, 64, 0, stream>>>(key,   Wk, bk, kp);
    proj_kernel<<<BB * NN, 64, 0, stream>>>(query, Wq, bq, qp);

    dim3 g2(BB * NN, NN / 64);
    attn_kernel<<<g2, 64, 0, stream>>>(kp, qp, wf, bf, attn);

    dim3 g3(NN / 64, CIN / 4, BB);
    av_kernel<<<g3, 64, 0, stream>>>(attn, value, out);
}

// Round 2
// 203.034 us; speedup vs baseline: 1.0342x; 1.0342x over previous
//
#include <hip/hip_runtime.h>
#include <hip/hip_bf16.h>

#define BB 4
#define CIN 256      // CK == CQ == CV
#define CO 64
#define NN 576       // 24*24

// ------------------------------------------------------------------
// transpose x[b,c,n] -> xt[b,n,c], both key and query in one launch.
// grid: (NN/32, CIN/32, 2*BB); block (32,8)
__global__ void transpose_kernel(const float* __restrict__ key,
                                 const float* __restrict__ query,
                                 float* __restrict__ kt,
                                 float* __restrict__ qt) {
    int z = blockIdx.z;
    const float* src = (z < BB) ? key : query;
    float* dst       = (z < BB) ? kt  : qt;
    int b = z & (BB - 1);
    __shared__ float tile[32][33];
    int n0 = blockIdx.x * 32, c0 = blockIdx.y * 32;
    int tx = threadIdx.x, ty = threadIdx.y;
    const float* s = src + (size_t)b * CIN * NN;
    #pragma unroll
    for (int j = 0; j < 4; ++j) {
        int c = c0 + ty + j * 8;
        tile[ty + j * 8][tx] = s[(size_t)c * NN + n0 + tx];
    }
    __syncthreads();
    float* d = dst + (size_t)b * NN * CIN;
    #pragma unroll
    for (int j = 0; j < 4; ++j) {
        int n = n0 + ty + j * 8;
        d[(size_t)n * CIN + c0 + tx] = tile[tx][ty + j * 8];
    }
}

// ------------------------------------------------------------------
// proj + exp: P[b,n,o] = exp(2*(sum_c xt[b,n,c]*W[o,c] + bias[o]))
// lane = o; NT n-rows per 64-thread block. W chunk in VGPRs, x rows are
// wave-uniform -> scalar loads. grid: (NN/NT, BB, 2)
#define NT 8
__global__ void proj_exp_kernel(const float* __restrict__ kt,
                                const float* __restrict__ qt,
                                const float* __restrict__ Wk, const float* __restrict__ bk,
                                const float* __restrict__ Wq, const float* __restrict__ bq,
                                float* __restrict__ ek, float* __restrict__ eq) {
    int z = blockIdx.z;
    const float* xt   = z ? qt : kt;
    const float* W    = z ? Wq : Wk;
    const float* bias = z ? bq : bk;
    float* outp       = z ? eq : ek;
    int b  = blockIdx.y;
    int n0 = blockIdx.x * NT;
    int o  = threadIdx.x;

    float acc[NT];
    float bv = bias[o];
    #pragma unroll
    for (int i = 0; i < NT; ++i) acc[i] = bv;

    const float* wrow  = W + (size_t)o * CIN;
    const float* xbase = xt + ((size_t)b * NN + n0) * CIN;

    for (int c0 = 0; c0 < CIN; c0 += 64) {
        float4 w[16];
        #pragma unroll
        for (int i = 0; i < 16; ++i) w[i] = ((const float4*)(wrow + c0))[i];
        #pragma unroll
        for (int n = 0; n < NT; ++n) {
            const float* xr = xbase + (size_t)n * CIN + c0;
            #pragma unroll
            for (int i = 0; i < 16; ++i) {
                float4 wv = w[i];
                acc[n] = fmaf(wv.x, xr[4 * i + 0], acc[n]);
                acc[n] = fmaf(wv.y, xr[4 * i + 1], acc[n]);
                acc[n] = fmaf(wv.z, xr[4 * i + 2], acc[n]);
                acc[n] = fmaf(wv.w, xr[4 * i + 3], acc[n]);
            }
        }
    }
    float* op = outp + ((size_t)b * NN + n0) * CO + o;
    #pragma unroll
    for (int i = 0; i < NT; ++i) op[(size_t)i * CO] = __expf(2.0f * acc[i]);
}

// ------------------------------------------------------------------
// attn[b,k,q] = sigmoid( C - sum_o 2*wf[o] / (1 + ek[b,k,o]*eq[b,q,o]) )
// C = sum_o wf[o] + bf.  Block 256 = 4 waves; lane = q (tile 64),
// each wave 8 k (k-tile 32/block). grid: (NN/64, NN/32, BB)
__global__ void attn_kernel(const float* __restrict__ ek,
                            const float* __restrict__ eq,
                            const float* __restrict__ wf,
                            const float* __restrict__ bfp,
                            float* __restrict__ attn) {
    int b  = blockIdx.z;
    int k0 = blockIdx.y * 32;
    int q0 = blockIdx.x * 64;
    int t  = threadIdx.x;
    int l  = t & 63;
    int w  = t >> 6;

    __shared__ float eqs[64][68];   // pad 4 keeps 16B alignment, spreads banks
    __shared__ float w2s[64];
    __shared__ float Cs;

    #pragma unroll
    for (int i = 0; i < 16; ++i) {
        int q = (t >> 6) + i * 4;
        eqs[q][l] = eq[((size_t)b * NN + q0 + q) * CO + l];
    }
    if (t < 64) {
        float v = wf[t];
        w2s[t] = 2.0f * v;
        #pragma unroll
        for (int s = 32; s; s >>= 1) v += __shfl_xor(v, s, 64);
        if (t == 0) Cs = v + bfp[0];
    }
    __syncthreads();
    float C = Cs;
    const float* eql = &eqs[l][0];

    #pragma unroll 1
    for (int kk = 0; kk < 8; ++kk) {
        int k = __builtin_amdgcn_readfirstlane(k0 + w * 8 + kk);
        const float* ekrow = ek + ((size_t)b * NN + k) * CO;
        float a0 = 0.f, a1 = 0.f, a2 = 0.f, a3 = 0.f;
        #pragma unroll
        for (int i = 0; i < 16; ++i) {
            float4 e4 = *(const float4*)(eql + 4 * i);
            float4 k4 = *(const float4*)(ekrow + 4 * i);
            float4 w4 = *(const float4*)&w2s[4 * i];
            a0 = fmaf(w4.x, __builtin_amdgcn_rcpf(fmaf(k4.x, e4.x, 1.0f)), a0);
            a1 = fmaf(w4.y, __builtin_amdgcn_rcpf(fmaf(k4.y, e4.y, 1.0f)), a1);
            a2 = fmaf(w4.z, __builtin_amdgcn_rcpf(fmaf(k4.z, e4.z, 1.0f)), a2);
            a3 = fmaf(w4.w, __builtin_amdgcn_rcpf(fmaf(k4.w, e4.w, 1.0f)), a3);
        }
        float score = C - (a0 + a1) - (a2 + a3);
        float sg = __builtin_amdgcn_rcpf(1.0f + __expf(-score));
        attn[((size_t)b * NN + k) * NN + q0 + l] = sg;
    }
}

// ------------------------------------------------------------------
// out[b,c,q] = sum_k attn[b,k,q] * value[b,c,k]
// Block 256: 64c x 64q tile, k-chunks of 32. lane = q, wave w -> 16 c.
// grid: (NN/64, CIN/64, BB)
#define KC 32
__global__ void av_kernel(const float* __restrict__ attn,
                          const float* __restrict__ value,
                          float* __restrict__ out) {
    int b  = blockIdx.z;
    int c0 = blockIdx.y * 64;
    int q0 = blockIdx.x * 64;
    int t  = threadIdx.x;
    int l  = t & 63;
    int w  = t >> 6;

    __shared__ float as[KC][64];
    __shared__ float vs[64][KC];

    float acc[16];
    #pragma unroll
    for (int j = 0; j < 16; ++j) acc[j] = 0.f;

    for (int k0 = 0; k0 < NN; k0 += KC) {
        __syncthreads();
        #pragma unroll
        for (int i = 0; i < 8; ++i) {
            int kk = (t >> 6) + i * 4;
            as[kk][l] = attn[((size_t)b * NN + k0 + kk) * NN + q0 + l];
        }
        #pragma unroll
        for (int i = 0; i < 8; ++i) {
            int c  = (t >> 5) + i * 8;
            int kk = t & 31;
            vs[c][kk] = value[((size_t)b * CIN + c0 + c) * NN + k0 + kk];
        }
        __syncthreads();
        #pragma unroll
        for (int kk = 0; kk < KC; kk += 4) {
            float a0 = as[kk + 0][l];
            float a1 = as[kk + 1][l];
            float a2 = as[kk + 2][l];
            float a3 = as[kk + 3][l];
            #pragma unroll
            for (int j = 0; j < 16; ++j) {
                float4 v4 = *(const float4*)&vs[w * 16 + j][kk];
                acc[j] = fmaf(a0, v4.x, acc[j]);
                acc[j] = fmaf(a1, v4.y, acc[j]);
                acc[j] = fmaf(a2, v4.z, acc[j]);
                acc[j] = fmaf(a3, v4.w, acc[j]);
            }
        }
    }
    #pragma unroll
    for (int j = 0; j < 16; ++j)
        out[((size_t)b * CIN + c0 + w * 16 + j) * NN + q0 + l] = acc[j];
}

// ------------------------------------------------------------------
extern "C" void kernel_launch(void* const* d_in, const int* in_sizes, int n_in,
                              void* d_out, int out_size, void* d_ws, size_t ws_size,
                              hipStream_t stream) {
    const float* key   = (const float*)d_in[0];
    const float* query = (const float*)d_in[1];
    const float* value = (const float*)d_in[2];
    const float* Wk    = (const float*)d_in[3];
    const float* bk    = (const float*)d_in[4];
    const float* Wq    = (const float*)d_in[5];
    const float* bq    = (const float*)d_in[6];
    const float* wf    = (const float*)d_in[7];
    const float* bf    = (const float*)d_in[8];
    float* out = (float*)d_out;

    float* ws   = (float*)d_ws;
    float* ek   = ws;                              // 4*576*64   = 147456
    float* eq   = ek + (size_t)BB * NN * CO;       // 147456
    float* kt   = eq + (size_t)BB * NN * CO;       // 4*576*256  = 589824
    float* qt   = kt + (size_t)BB * NN * CIN;      // 589824
    float* attn = kt;                              // reuse kt/qt space: 1327104

    dim3 gt(NN / 32, CIN / 32, 2 * BB);
    transpose_kernel<<<gt, dim3(32, 8), 0, stream>>>(key, query, kt, qt);

    dim3 gp(NN / NT, BB, 2);
    proj_exp_kernel<<<gp, 64, 0, stream>>>(kt, qt, Wk, bk, Wq, bq, ek, eq);

    dim3 ga(NN / 64, NN / 32, BB);
    attn_kernel<<<ga, 256, 0, stream>>>(ek, eq, wf, bf, attn);

    dim3 gv(NN / 64, CIN / 64, BB);
    av_kernel<<<gv, 256, 0, stream>>>(attn, value, out);
}

// Round 3
// 116.804 us; speedup vs baseline: 1.7977x; 1.7382x over previous
//
#include <hip/hip_runtime.h>
#include <hip/hip_bf16.h>

#define BB 4
#define CIN 256      // CK == CQ == CV
#define CO 64
#define NN 576       // 24*24
#define NKC 18       // k-chunks of 32
#define NQT 36       // q-subtiles of 16

typedef __attribute__((ext_vector_type(8))) short short8;
typedef __attribute__((ext_vector_type(4))) float floatx4;

__device__ __forceinline__ unsigned short f2bf(float f) {
    unsigned int u = __float_as_uint(f);
    unsigned int r = (u + 0x7fffu + ((u >> 16) & 1u)) >> 16;   // RNE
    return (unsigned short)r;
}

// ------------------------------------------------------------------
// transpose x[b,c,n] -> xt[b,n,c], key and query in one launch.
// grid: (NN/32, CIN/32, 2*BB); block (32,8)
__global__ void transpose_kernel(const float* __restrict__ key,
                                 const float* __restrict__ query,
                                 float* __restrict__ kt,
                                 float* __restrict__ qt) {
    int z = blockIdx.z;
    const float* src = (z < BB) ? key : query;
    float* dst       = (z < BB) ? kt  : qt;
    int b = z & (BB - 1);
    __shared__ float tile[32][33];
    int n0 = blockIdx.x * 32, c0 = blockIdx.y * 32;
    int tx = threadIdx.x, ty = threadIdx.y;
    const float* s = src + (size_t)b * CIN * NN;
    #pragma unroll
    for (int j = 0; j < 4; ++j) {
        int c = c0 + ty + j * 8;
        tile[ty + j * 8][tx] = s[(size_t)c * NN + n0 + tx];
    }
    __syncthreads();
    float* d = dst + (size_t)b * NN * CIN;
    #pragma unroll
    for (int j = 0; j < 4; ++j) {
        int n = n0 + ty + j * 8;
        d[(size_t)n * CIN + c0 + tx] = tile[tx][ty + j * 8];
    }
}

// ------------------------------------------------------------------
// proj + exp: P[b,n,o] = exp(2*(sum_c xt[b,n,c]*W[o,c] + bias[o]))
// lane = o; NT n-rows per 64-thread wave-block. grid: (NN/NT, BB, 2)
#define NT 4
__global__ void proj_exp_kernel(const float* __restrict__ kt,
                                const float* __restrict__ qt,
                                const float* __restrict__ Wk, const float* __restrict__ bk,
                                const float* __restrict__ Wq, const float* __restrict__ bq,
                                float* __restrict__ ek, float* __restrict__ eq) {
    int z = blockIdx.z;
    const float* xt   = z ? qt : kt;
    const float* W    = z ? Wq : Wk;
    const float* bias = z ? bq : bk;
    float* outp       = z ? eq : ek;
    int b  = blockIdx.y;
    int n0 = blockIdx.x * NT;
    int o  = threadIdx.x;

    float acc[NT];
    float bv = bias[o];
    #pragma unroll
    for (int i = 0; i < NT; ++i) acc[i] = bv;

    const float* wrow  = W + (size_t)o * CIN;
    const float* xbase = xt + ((size_t)b * NN + n0) * CIN;

    for (int c0 = 0; c0 < CIN; c0 += 64) {
        float4 w[16];
        #pragma unroll
        for (int i = 0; i < 16; ++i) w[i] = ((const float4*)(wrow + c0))[i];
        #pragma unroll
        for (int n = 0; n < NT; ++n) {
            const float* xr = xbase + (size_t)n * CIN + c0;
            #pragma unroll
            for (int i = 0; i < 16; ++i) {
                float4 wv = w[i];
                acc[n] = fmaf(wv.x, xr[4 * i + 0], acc[n]);
                acc[n] = fmaf(wv.y, xr[4 * i + 1], acc[n]);
                acc[n] = fmaf(wv.z, xr[4 * i + 2], acc[n]);
                acc[n] = fmaf(wv.w, xr[4 * i + 3], acc[n]);
            }
        }
    }
    float* op = outp + ((size_t)b * NN + n0) * CO + o;
    #pragma unroll
    for (int i = 0; i < NT; ++i) op[(size_t)i * CO] = __expf(2.0f * acc[i]);
}

// ------------------------------------------------------------------
// pack value -> bf16 MFMA A-fragments.
// Vp[((b*16+ct)*18+kc)*1024 + lane*8 + j] = bf16(V[b][ct*16+(l&15)][kc*32+(l>>4)*8+j])
// grid: (16, 18, BB); block 64
__global__ void packv_kernel(const float* __restrict__ value,
                             unsigned short* __restrict__ Vp) {
    int ct = blockIdx.x, kc = blockIdx.y, b = blockIdx.z;
    int l = threadIdx.x;
    int c = ct * 16 + (l & 15);
    int k = kc * 32 + (l >> 4) * 8;
    const float4* src = (const float4*)(value + ((size_t)b * CIN + c) * NN + k);
    float4 v0 = src[0], v1 = src[1];
    uint4 o;
    o.x = (unsigned)f2bf(v0.x) | ((unsigned)f2bf(v0.y) << 16);
    o.y = (unsigned)f2bf(v0.z) | ((unsigned)f2bf(v0.w) << 16);
    o.z = (unsigned)f2bf(v1.x) | ((unsigned)f2bf(v1.y) << 16);
    o.w = (unsigned)f2bf(v1.z) | ((unsigned)f2bf(v1.w) << 16);
    *(uint4*)(Vp + (((size_t)b * 16 + ct) * NKC + kc) * 1024 + l * 8) = o;
}

// ------------------------------------------------------------------
// attn scores + sigmoid + bf16 B-fragment pack.
// score(k,q) = C - sum_o 2*wf[o] / (1 + ek[k,o]*eq[q,o]),  C = sum wf + bf
// block: 256 thr = 4 waves; q-tile 64 (lane=q), k-tile 32 (wave w -> 8 k).
// grid: (NN/64, NN/32, BB)
__global__ void __launch_bounds__(256, 3)
attn_pack_kernel(const float* __restrict__ ek,
                 const float* __restrict__ eq,
                 const float* __restrict__ wf,
                 const float* __restrict__ bfp,
                 unsigned short* __restrict__ Bp) {
    int b  = blockIdx.z;
    int k0 = blockIdx.y * 32;
    int q0 = blockIdx.x * 64;
    int t  = threadIdx.x;
    int l  = t & 63;
    int w  = __builtin_amdgcn_readfirstlane(t >> 6);

    // per-lane q-row (64 floats) and wf*2 (64 floats) in VGPRs
    float4 eqv[16], w2v[16];
    const float4* eqp = (const float4*)(eq + ((size_t)b * NN + q0 + l) * CO);
    const float4* wfp = (const float4*)wf;
    float C = bfp[0];
    #pragma unroll
    for (int i = 0; i < 16; ++i) {
        eqv[i] = eqp[i];
        float4 wv = wfp[i];
        C += wv.x + wv.y + wv.z + wv.w;
        wv.x *= 2.0f; wv.y *= 2.0f; wv.z *= 2.0f; wv.w *= 2.0f;
        w2v[i] = wv;
    }

    __shared__ float sc[32][64];

    #pragma unroll 1
    for (int kk = 0; kk < 8; ++kk) {
        int k = k0 + w * 8 + kk;     // wave-uniform
        const float4* ekr = (const float4*)(ek + ((size_t)b * NN + k) * CO);
        float a0 = 0.f, a1 = 0.f, a2 = 0.f, a3 = 0.f;
        #pragma unroll
        for (int i = 0; i < 16; ++i) {
            float4 k4 = ekr[i];
            float4 e4 = eqv[i];
            float4 w4 = w2v[i];
            a0 = fmaf(w4.x, __builtin_amdgcn_rcpf(fmaf(k4.x, e4.x, 1.0f)), a0);
            a1 = fmaf(w4.y, __builtin_amdgcn_rcpf(fmaf(k4.y, e4.y, 1.0f)), a1);
            a2 = fmaf(w4.z, __builtin_amdgcn_rcpf(fmaf(k4.z, e4.z, 1.0f)), a2);
            a3 = fmaf(w4.w, __builtin_amdgcn_rcpf(fmaf(k4.w, e4.w, 1.0f)), a3);
        }
        float score = C - (a0 + a1) - (a2 + a3);
        float sg = __builtin_amdgcn_rcpf(1.0f + __expf(-score));
        sc[w * 8 + kk][l] = sg;
    }
    __syncthreads();

    // pack: wave w -> q-subtile qt = w; lane element j = sc[(l>>4)*8+j][w*16+(l&15)]
    int col = w * 16 + (l & 15);
    int row = (l >> 4) * 8;
    uint4 o;
    o.x = (unsigned)f2bf(sc[row + 0][col]) | ((unsigned)f2bf(sc[row + 1][col]) << 16);
    o.y = (unsigned)f2bf(sc[row + 2][col]) | ((unsigned)f2bf(sc[row + 3][col]) << 16);
    o.z = (unsigned)f2bf(sc[row + 4][col]) | ((unsigned)f2bf(sc[row + 5][col]) << 16);
    o.w = (unsigned)f2bf(sc[row + 6][col]) | ((unsigned)f2bf(sc[row + 7][col]) << 16);
    size_t qt = (size_t)blockIdx.x * 4 + w;
    *(uint4*)(Bp + (((size_t)b * NQT + qt) * NKC + blockIdx.y) * 1024 + l * 8) = o;
}

// ------------------------------------------------------------------
// out[b,c,q] = sum_k V[b,c,k] * attn[b,k,q] via mfma_f32_16x16x32_bf16.
// block 256 = 4 waves; block tile: ct (16 c) x 64 q (4 subtiles); wave w
// takes kc = w, w+4, ... (k-split 4) then LDS reduce.
// grid: (NN/64, 16, BB)
__global__ void av_mfma_kernel(const unsigned short* __restrict__ Vp,
                               const unsigned short* __restrict__ Bp,
                               float* __restrict__ out) {
    int b  = blockIdx.z;
    int ct = blockIdx.y;
    int qx = blockIdx.x;
    int t  = threadIdx.x;
    int l  = t & 63;
    int w  = __builtin_amdgcn_readfirstlane(t >> 6);

    floatx4 acc[4] = {{0.f,0.f,0.f,0.f},{0.f,0.f,0.f,0.f},
                      {0.f,0.f,0.f,0.f},{0.f,0.f,0.f,0.f}};

    const unsigned short* abase = Vp + ((size_t)b * 16 + ct) * NKC * 1024 + l * 8;
    const unsigned short* bbase = Bp + ((size_t)b * NQT + (size_t)qx * 4) * NKC * 1024 + l * 8;

    for (int kc = w; kc < NKC; kc += 4) {
        short8 a = *(const short8*)(abase + (size_t)kc * 1024);
        #pragma unroll
        for (int qt = 0; qt < 4; ++qt) {
            short8 bq = *(const short8*)(bbase + ((size_t)qt * NKC + kc) * 1024);
            acc[qt] = __builtin_amdgcn_mfma_f32_16x16x32_bf16(a, bq, acc[qt], 0, 0, 0);
        }
    }

    __shared__ float red[4][64][17];
    #pragma unroll
    for (int qt = 0; qt < 4; ++qt)
        #pragma unroll
        for (int r = 0; r < 4; ++r)
            red[w][l][qt * 4 + r] = acc[qt][r];
    __syncthreads();

    // wave w combines and stores q-subtile qt = w
    int q = qx * 64 + w * 16 + (l & 15);
    #pragma unroll
    for (int r = 0; r < 4; ++r) {
        float s = red[0][l][w * 4 + r] + red[1][l][w * 4 + r]
                + red[2][l][w * 4 + r] + red[3][l][w * 4 + r];
        int c = ct * 16 + (l >> 4) * 4 + r;
        out[((size_t)b * CIN + c) * NN + q] = s;
    }
}

// ------------------------------------------------------------------
extern "C" void kernel_launch(void* const* d_in, const int* in_sizes, int n_in,
                              void* d_out, int out_size, void* d_ws, size_t ws_size,
                              hipStream_t stream) {
    const float* key   = (const float*)d_in[0];
    const float* query = (const float*)d_in[1];
    const float* value = (const float*)d_in[2];
    const float* Wk    = (const float*)d_in[3];
    const float* bk    = (const float*)d_in[4];
    const float* Wq    = (const float*)d_in[5];
    const float* bq    = (const float*)d_in[6];
    const float* wf    = (const float*)d_in[7];
    const float* bf    = (const float*)d_in[8];
    float* out = (float*)d_out;

    float* ws = (float*)d_ws;
    float* ek = ws;                               // 4*576*64 = 147456 f
    float* eq = ek + (size_t)BB * NN * CO;        // 147456 f
    float* bp_region = eq + (size_t)BB * NN * CO; // 1327104 f (= Bp, 5.3MB)
    unsigned short* Bp = (unsigned short*)bp_region;
    // kt/qt alias the Bp region (dead before attn_pack writes Bp)
    float* kt = bp_region;                        // 589824 f
    float* qt = kt + (size_t)BB * NN * CIN;       // 589824 f (fits: 1179648 < 1327104)
    unsigned short* Vp = (unsigned short*)(bp_region + 1327104); // 589824 f worth

    dim3 gt(NN / 32, CIN / 32, 2 * BB);
    transpose_kernel<<<gt, dim3(32, 8), 0, stream>>>(key, query, kt, qt);

    dim3 gp(NN / NT, BB, 2);
    proj_exp_kernel<<<gp, 64, 0, stream>>>(kt, qt, Wk, bk, Wq, bq, ek, eq);

    dim3 gv(16, NKC, BB);
    packv_kernel<<<gv, 64, 0, stream>>>(value, Vp);

    dim3 ga(NN / 64, NN / 32, BB);
    attn_pack_kernel<<<ga, 256, 0, stream>>>(ek, eq, wf, bf, Bp);

    dim3 gm(NN / 64, 16, BB);
    av_mfma_kernel<<<gm, 256, 0, stream>>>(Vp, Bp, out);
}

// Round 4
// 102.326 us; speedup vs baseline: 2.0521x; 1.1415x over previous
//
#include <hip/hip_runtime.h>
#include <hip/hip_bf16.h>

#define BB 4
#define CIN 256      // CK == CQ == CV
#define CO 64
#define NN 576       // 24*24
#define NKC 18       // 576/32 k-chunks
#define NMT 36       // 576/16 row-subtiles
#define NQT 36       // q-subtiles of 16

typedef __attribute__((ext_vector_type(8))) short short8;
typedef __attribute__((ext_vector_type(4))) float floatx4;

__device__ __forceinline__ unsigned short f2bf(float f) {
    unsigned int u = __float_as_uint(f);
    unsigned int r = (u + 0x7fffu + ((u >> 16) & 1u)) >> 16;   // RNE
    return (unsigned short)r;
}

// ------------------------------------------------------------------
// One kernel packs everything to bf16 MFMA fragments:
//   bids [0,1152):    x (key z=0 / query z=1) -> Xp A-fragments (LDS transpose)
//   bids [1152,1168): W (Wk/Wq) -> Wp B-fragments
//   bids [1168,1456): value -> Vp A-fragments
// Fragment = 64 lanes x 8 elems = 512 ushorts.
// A-frag: elem j of lane l = M[m0 + (l&15)][k0 + (l>>4)*8 + j]
// B-frag: elem j of lane l = B[k0 + (l>>4)*8 + j][n0 + (l&15)]
__global__ void __launch_bounds__(256) pack_all(
    const float* __restrict__ key, const float* __restrict__ query,
    const float* __restrict__ value,
    const float* __restrict__ Wk, const float* __restrict__ Wq,
    unsigned short* __restrict__ Xp, unsigned short* __restrict__ Wp,
    unsigned short* __restrict__ Vp)
{
    __shared__ float tile[32][33];
    int bid = blockIdx.x;
    int t = threadIdx.x;
    int l = t & 63;
    int w = t >> 6;

    if (bid < 1152) {
        // ---- x pack: 32n x 32c tile per block ----
        int zb  = bid / 144;           // z*4 + b
        int r   = bid % 144;
        int n32 = r % 18;
        int kc  = r / 18;              // c-tile of 32 == kc in [0,8)
        int z = zb >> 2, b = zb & 3;
        const float* src = z ? query : key;
        int tx = t & 31, ty = t >> 5;  // ty 0..7
        const float* s = src + ((size_t)b * CIN + (size_t)kc * 32) * NN + n32 * 32;
        #pragma unroll
        for (int j = 0; j < 4; ++j) {
            int cl = ty + j * 8;
            tile[cl][tx] = s[(size_t)cl * NN + tx];
        }
        __syncthreads();
        if (w < 2) {
            int nl = w * 16 + (l & 15);
            int cl = (l >> 4) * 8;
            uint4 o;
            o.x = (unsigned)f2bf(tile[cl + 0][nl]) | ((unsigned)f2bf(tile[cl + 1][nl]) << 16);
            o.y = (unsigned)f2bf(tile[cl + 2][nl]) | ((unsigned)f2bf(tile[cl + 3][nl]) << 16);
            o.z = (unsigned)f2bf(tile[cl + 4][nl]) | ((unsigned)f2bf(tile[cl + 5][nl]) << 16);
            o.w = (unsigned)f2bf(tile[cl + 6][nl]) | ((unsigned)f2bf(tile[cl + 7][nl]) << 16);
            int mt = n32 * 2 + w;
            *(uint4*)(Xp + ((((size_t)z * BB + b) * NMT + mt) * 8 + kc) * 512 + l * 8) = o;
        }
    } else if (bid < 1168) {
        // ---- W pack: 4 fragment-units per block (one per wave) ----
        int funit = (bid - 1152) * 4 + w;     // 0..63
        int z  = funit >> 5;
        int nt = (funit >> 3) & 3;
        int kc = funit & 7;
        const float* W = z ? Wq : Wk;
        int o = nt * 16 + (l & 15);
        int c = kc * 32 + (l >> 4) * 8;
        const float4* p = (const float4*)(W + (size_t)o * CIN + c);
        float4 v0 = p[0], v1 = p[1];
        uint4 u;
        u.x = (unsigned)f2bf(v0.x) | ((unsigned)f2bf(v0.y) << 16);
        u.y = (unsigned)f2bf(v0.z) | ((unsigned)f2bf(v0.w) << 16);
        u.z = (unsigned)f2bf(v1.x) | ((unsigned)f2bf(v1.y) << 16);
        u.w = (unsigned)f2bf(v1.z) | ((unsigned)f2bf(v1.w) << 16);
        *(uint4*)(Wp + (((size_t)z * 4 + nt) * 8 + kc) * 512 + l * 8) = u;
    } else {
        // ---- V pack: 4 fragment-units per block ----
        int funit = (bid - 1168) * 4 + w;     // 0..1151
        int b  = funit / 288;
        int r  = funit % 288;
        int ct = r / 18;
        int kc = r % 18;
        int c = ct * 16 + (l & 15);
        int k = kc * 32 + (l >> 4) * 8;
        const float4* p = (const float4*)(value + ((size_t)b * CIN + c) * NN + k);
        float4 v0 = p[0], v1 = p[1];
        uint4 u;
        u.x = (unsigned)f2bf(v0.x) | ((unsigned)f2bf(v0.y) << 16);
        u.y = (unsigned)f2bf(v0.z) | ((unsigned)f2bf(v0.w) << 16);
        u.z = (unsigned)f2bf(v1.x) | ((unsigned)f2bf(v1.y) << 16);
        u.w = (unsigned)f2bf(v1.z) | ((unsigned)f2bf(v1.w) << 16);
        *(uint4*)(Vp + (((size_t)b * 16 + ct) * NKC + kc) * 512 + l * 8) = u;
    }
}

// ------------------------------------------------------------------
// proj via MFMA + fused exp:  e[b,n,o] = exp(2*(sum_c x[b,c,n]*W[o,c] + bias[o]))
// one wave per (z, b, mt): 8 kc x 4 nt = 32 MFMA. grid: 72 blocks x 256.
__global__ void __launch_bounds__(256) proj_exp_mfma(
    const unsigned short* __restrict__ Xp, const unsigned short* __restrict__ Wp,
    const float* __restrict__ bk, const float* __restrict__ bq,
    float* __restrict__ ek, float* __restrict__ eq)
{
    int t = threadIdx.x, l = t & 63, w = t >> 6;
    int gw = blockIdx.x * 4 + w;    // 0..287
    int z  = gw / 144;
    int r  = gw % 144;
    int b  = r / NMT;
    int mt = r % NMT;

    const unsigned short* ab = Xp + ((((size_t)z * BB + b) * NMT + mt) * 8) * 512 + l * 8;
    const unsigned short* wb = Wp + (size_t)z * 32 * 512 + l * 8;

    floatx4 acc[4] = {{0.f,0.f,0.f,0.f},{0.f,0.f,0.f,0.f},
                      {0.f,0.f,0.f,0.f},{0.f,0.f,0.f,0.f}};
    #pragma unroll
    for (int kc = 0; kc < 8; ++kc) {
        short8 a = *(const short8*)(ab + (size_t)kc * 512);
        #pragma unroll
        for (int nt = 0; nt < 4; ++nt) {
            short8 bf8 = *(const short8*)(wb + ((size_t)nt * 8 + kc) * 512);
            acc[nt] = __builtin_amdgcn_mfma_f32_16x16x32_bf16(a, bf8, acc[nt], 0, 0, 0);
        }
    }

    const float* bias = z ? bq : bk;
    float* outp       = z ? eq : ek;
    int n0 = mt * 16;
    #pragma unroll
    for (int nt = 0; nt < 4; ++nt) {
        int o = nt * 16 + (l & 15);
        float bv = bias[o];
        #pragma unroll
        for (int rr = 0; rr < 4; ++rr) {
            int row = (l >> 4) * 4 + rr;
            outp[((size_t)b * NN + n0 + row) * CO + o] = __expf(2.0f * (acc[nt][rr] + bv));
        }
    }
}

// ------------------------------------------------------------------
// attn scores + sigmoid + bf16 B-fragment pack.
// score(k,q) = C - sum_o 2*wf[o]/(1 + ek[k,o]*eq[q,o]),  C = sum wf + bf.
// eq tile staged coalesced via LDS (stride-65 rows: conflict-free b32 reads),
// then lane-row in VGPRs; ek rows wave-uniform broadcast loads.
// grid: (NN/64, NN/32, BB), block 256 = 4 waves (wave w -> 8 k).
__global__ void __launch_bounds__(256, 3) attn_pack_kernel(
    const float* __restrict__ ek, const float* __restrict__ eq,
    const float* __restrict__ wf, const float* __restrict__ bfp,
    unsigned short* __restrict__ Bp)
{
    int b  = blockIdx.z;
    int k0 = blockIdx.y * 32;
    int q0 = blockIdx.x * 64;
    int t  = threadIdx.x;
    int l  = t & 63;
    int w  = __builtin_amdgcn_readfirstlane(t >> 6);

    __shared__ float eqs[64 * 65];
    __shared__ float sc[32 * 65];

    // coalesced global -> LDS (16 KB contiguous span)
    const float4* esrc = (const float4*)(eq + ((size_t)b * NN + q0) * CO);
    #pragma unroll
    for (int i = 0; i < 4; ++i) {
        int f4  = t + i * 256;                 // 0..1023
        int row = f4 >> 4, c4 = (f4 & 15) * 4;
        float4 v = esrc[f4];
        int a = row * 65 + c4;
        eqs[a + 0] = v.x; eqs[a + 1] = v.y; eqs[a + 2] = v.z; eqs[a + 3] = v.w;
    }

    float4 w2v[16];
    float C = bfp[0];
    const float4* wfp4 = (const float4*)wf;
    #pragma unroll
    for (int i = 0; i < 16; ++i) {
        float4 wv = wfp4[i];
        C += wv.x + wv.y + wv.z + wv.w;
        wv.x *= 2.0f; wv.y *= 2.0f; wv.z *= 2.0f; wv.w *= 2.0f;
        w2v[i] = wv;
    }
    __syncthreads();

    // lane l's q-row into VGPRs (2-way bank aliasing only = free)
    float4 eqv[16];
    #pragma unroll
    for (int i = 0; i < 16; ++i) {
        int a = l * 65 + i * 4;
        eqv[i].x = eqs[a]; eqv[i].y = eqs[a + 1];
        eqv[i].z = eqs[a + 2]; eqv[i].w = eqs[a + 3];
    }

    #pragma unroll 1
    for (int kk = 0; kk < 8; ++kk) {
        int k = k0 + w * 8 + kk;               // wave-uniform
        const float4* ekr = (const float4*)(ek + ((size_t)b * NN + k) * CO);
        float a0 = 0.f, a1 = 0.f, a2 = 0.f, a3 = 0.f;
        #pragma unroll
        for (int i = 0; i < 16; ++i) {
            float4 k4 = ekr[i];
            float4 e4 = eqv[i];
            float4 w4 = w2v[i];
            a0 = fmaf(w4.x, __builtin_amdgcn_rcpf(fmaf(k4.x, e4.x, 1.0f)), a0);
            a1 = fmaf(w4.y, __builtin_amdgcn_rcpf(fmaf(k4.y, e4.y, 1.0f)), a1);
            a2 = fmaf(w4.z, __builtin_amdgcn_rcpf(fmaf(k4.z, e4.z, 1.0f)), a2);
            a3 = fmaf(w4.w, __builtin_amdgcn_rcpf(fmaf(k4.w, e4.w, 1.0f)), a3);
        }
        float score = C - (a0 + a1) - (a2 + a3);
        float sg = __builtin_amdgcn_rcpf(1.0f + __expf(-score));
        sc[(w * 8 + kk) * 65 + l] = sg;
    }
    __syncthreads();

    // pack: wave w -> q-subtile w; fragment elem j = sc[(l>>4)*8+j][w*16+(l&15)]
    int col = w * 16 + (l & 15);
    int row = (l >> 4) * 8;
    uint4 o;
    o.x = (unsigned)f2bf(sc[(row + 0) * 65 + col]) | ((unsigned)f2bf(sc[(row + 1) * 65 + col]) << 16);
    o.y = (unsigned)f2bf(sc[(row + 2) * 65 + col]) | ((unsigned)f2bf(sc[(row + 3) * 65 + col]) << 16);
    o.z = (unsigned)f2bf(sc[(row + 4) * 65 + col]) | ((unsigned)f2bf(sc[(row + 5) * 65 + col]) << 16);
    o.w = (unsigned)f2bf(sc[(row + 6) * 65 + col]) | ((unsigned)f2bf(sc[(row + 7) * 65 + col]) << 16);
    size_t qt = (size_t)blockIdx.x * 4 + w;
    *(uint4*)(Bp + (((size_t)b * NQT + qt) * NKC + blockIdx.y) * 512 + l * 8) = o;
}

// ------------------------------------------------------------------
// out[b,c,q] = sum_k V[b,c,k]*attn[b,k,q] via mfma_f32_16x16x32_bf16.
// block 256 = 4 waves; tile 16c x 64q; wave w takes kc = w, w+4, ... then
// LDS k-split reduce. grid: (NN/64, 16, BB)
__global__ void __launch_bounds__(256) av_mfma_kernel(
    const unsigned short* __restrict__ Vp,
    const unsigned short* __restrict__ Bp,
    float* __restrict__ out)
{
    int b  = blockIdx.z;
    int ct = blockIdx.y;
    int qx = blockIdx.x;
    int t  = threadIdx.x;
    int l  = t & 63;
    int w  = __builtin_amdgcn_readfirstlane(t >> 6);

    floatx4 acc[4] = {{0.f,0.f,0.f,0.f},{0.f,0.f,0.f,0.f},
                      {0.f,0.f,0.f,0.f},{0.f,0.f,0.f,0.f}};

    const unsigned short* abase = Vp + ((size_t)b * 16 + ct) * NKC * 512 + l * 8;
    const unsigned short* bbase = Bp + ((size_t)b * NQT + (size_t)qx * 4) * NKC * 512 + l * 8;

    for (int kc = w; kc < NKC; kc += 4) {
        short8 a = *(const short8*)(abase + (size_t)kc * 512);
        #pragma unroll
        for (int qt = 0; qt < 4; ++qt) {
            short8 bq = *(const short8*)(bbase + ((size_t)qt * NKC + kc) * 512);
            acc[qt] = __builtin_amdgcn_mfma_f32_16x16x32_bf16(a, bq, acc[qt], 0, 0, 0);
        }
    }

    __shared__ float red[4][64][17];
    #pragma unroll
    for (int qt = 0; qt < 4; ++qt)
        #pragma unroll
        for (int r = 0; r < 4; ++r)
            red[w][l][qt * 4 + r] = acc[qt][r];
    __syncthreads();

    int q = qx * 64 + w * 16 + (l & 15);
    #pragma unroll
    for (int r = 0; r < 4; ++r) {
        float s = red[0][l][w * 4 + r] + red[1][l][w * 4 + r]
                + red[2][l][w * 4 + r] + red[3][l][w * 4 + r];
        int c = ct * 16 + (l >> 4) * 4 + r;
        out[((size_t)b * CIN + c) * NN + q] = s;
    }
}

// ------------------------------------------------------------------
extern "C" void kernel_launch(void* const* d_in, const int* in_sizes, int n_in,
                              void* d_out, int out_size, void* d_ws, size_t ws_size,
                              hipStream_t stream) {
    const float* key   = (const float*)d_in[0];
    const float* query = (const float*)d_in[1];
    const float* value = (const float*)d_in[2];
    const float* Wk    = (const float*)d_in[3];
    const float* bk    = (const float*)d_in[4];
    const float* Wq    = (const float*)d_in[5];
    const float* bq    = (const float*)d_in[6];
    const float* wf    = (const float*)d_in[7];
    const float* bf    = (const float*)d_in[8];
    float* out = (float*)d_out;

    float* ws = (float*)d_ws;
    float* ek = ws;                                        // 147456 f
    float* eq = ek + (size_t)BB * NN * CO;                 // 147456 f
    unsigned short* Xp = (unsigned short*)(eq + (size_t)BB * NN * CO);
    unsigned short* Wp = Xp + (size_t)2 * BB * NMT * 8 * 512;   // Xp: 1,179,648 us
    unsigned short* Vp = Wp + (size_t)2 * 4 * 8 * 512;          // Wp: 32,768 us
    unsigned short* Bp = Vp + (size_t)BB * 16 * NKC * 512;      // Vp: 589,824 us
    // Bp: 2592 * 512 us; total ws ~7.4 MB

    pack_all<<<1456, 256, 0, stream>>>(key, query, value, Wk, Wq, Xp, Wp, Vp);

    proj_exp_mfma<<<72, 256, 0, stream>>>(Xp, Wp, bk, bq, ek, eq);

    dim3 ga(NN / 64, NN / 32, BB);
    attn_pack_kernel<<<ga, 256, 0, stream>>>(ek, eq, wf, bf, Bp);

    dim3 gm(NN / 64, 16, BB);
    av_mfma_kernel<<<gm, 256, 0, stream>>>(Vp, Bp, out);
}